// Round 4
// baseline (161.128 us; speedup 1.0000x reference)
//
#include <hip/hip_runtime.h>

// MultiHeadAttn1D: N=4, C=256, T=2048, H=8, dk=dv=32.
// ws layout (bytes):
//   [0   , 4Mi ) Q_ws  bf16 B-frag (16x16x32): [nh(32)][qtile(128)][lane(64)][8]
//                lane=(t&15)+16*(d>>3), j=d&7   (Q pre-scaled by log2e/sqrt(32))
//   [4Mi , 8Mi ) K_ws  bf16 A-frag (16x16x32): [nh][ktile(128)][lane][8]
//   [8Mi ,12Mi ) V_ws  bf16 B-frag (16x16x16): [nh][kb(32)][dt(2)][sbp(2)][lane][8]
//   [12Mi,16Mi ) Xb    bf16 A-frag x: [n(4)][tt(128)][kc(8)][lane][8]
//   [16Mi,16.4Mi) Wb   bf16 B-frag W: [wi(3)][ot(16)][kc(8)][lane][8]
//   [20Mi, +KS*4Mi)        O_part bf16 [ks][nh][d(32)][t(2048)]    (KS>1 only)
//   [20Mi+KS*4Mi, +KS*256Ki) l_part fp32 [ks][nh][t(2048)]         (KS>1 only)
//
// R8 = MEASUREMENT ROUND. Kernels byte-identical to R7/R6. attn_kernel<2> is
// launched 3x (idempotent: deterministic overwrite of opart/lpart from
// unchanged ws; no atomics, no accumulation across launches). dur_us now =
// base + 2*T_attn, resolving whether attn is ~16us (issue model) or ~35us
// (latency-bound) -- the per-kernel split is invisible in rocprof top-5
// because the harness's 41us ws-poison fills occupy all five slots.

typedef float f32x4 __attribute__((ext_vector_type(4)));
typedef short short8 __attribute__((ext_vector_type(8)));
typedef short short4v __attribute__((ext_vector_type(4)));

#define WS_Q 0u
#define WS_K (4u << 20)
#define WS_V (8u << 20)
#define WS_X (12u << 20)
#define WS_W (16u << 20)
#define WS_OP (20u << 20)

__device__ __forceinline__ unsigned short f2bf(float f) {
  unsigned int u = __builtin_bit_cast(unsigned int, f);
  u += 0x7FFFu + ((u >> 16) & 1u);
  return (unsigned short)(u >> 16);
}

// pack two floats to bf16 into one dword: [bf(a) | bf(b)<<16]
__device__ __forceinline__ int pack_bf16rn(float a, float b) {
  unsigned int ua = __builtin_bit_cast(unsigned int, a) + 0x8000u;
  unsigned int ub = __builtin_bit_cast(unsigned int, b) + 0x8000u;
  return __builtin_amdgcn_perm(ub, ua, 0x07060302);
}

// ---------------- pack: x -> Xb (bf16 A-frags), W -> Wb (bf16 B-frags) ---------
__global__ __launch_bounds__(256) void pack_kernel(
    const float* __restrict__ x, const float* __restrict__ Wq,
    const float* __restrict__ Wk, const float* __restrict__ Wv,
    unsigned short* __restrict__ ws) {
  const int tid = threadIdx.x;
  const int lane = tid & 63;
  const int wv = tid >> 6;
  const int lc = lane & 15, lq = lane >> 4;
  const int b = blockIdx.x;
  alignas(16) unsigned short tmp[8];
  if (b < 1024) {
    const int r = b * 4 + wv;  // 0..4095 = (n,tt,kc)
    const int kc = r & 7, tt = (r >> 3) & 127, n = r >> 10;
    const int t = tt * 16 + lc;
    const int c0 = kc * 32 + lq * 8;
    const float* src = x + (size_t)(n * 256 + c0) * 2048 + t;
#pragma unroll
    for (int j = 0; j < 8; ++j) tmp[j] = f2bf(src[(size_t)j * 2048]);
    unsigned short* dst = ws + (WS_X >> 1) + (size_t)r * 512 + lane * 8;
    *(int4*)dst = *(const int4*)tmp;
  } else {
    const int r = (b - 1024) * 4 + wv;  // 0..383 = (wi,ot,kc)
    const int kc = r & 7, ot = (r >> 3) & 15, wi = r >> 7;
    const float* W = (wi == 0) ? Wq : (wi == 1) ? Wk : Wv;
    const float scale = (wi == 0) ? 0.25503492f : 1.0f;  // log2(e)/sqrt(32)
    const int o = ot * 16 + lc;
    const int c0 = kc * 32 + lq * 8;
    const float* src = W + o * 256 + c0;
#pragma unroll
    for (int j = 0; j < 8; ++j) tmp[j] = f2bf(src[j] * scale);
    unsigned short* dst = ws + (WS_W >> 1) + (size_t)r * 512 + lane * 8;
    *(int4*)dst = *(const int4*)tmp;
  }
}

// ---------------- projection GEMM: Q/K/V = W * x, frag-packed outputs ----------
__global__ __launch_bounds__(256) void proj_kernel(unsigned short* __restrict__ ws) {
  __shared__ unsigned short eps[4][2048];  // per-wave 4KB swizzle buffer (Q/K only)
  const int tid = threadIdx.x, lane = tid & 63, w = tid >> 6;
  const int lc = lane & 15, lq = lane >> 4;
  const int tt2 = blockIdx.x;  // 0..63 : t-range of 32
  const int n = blockIdx.y;    // 0..3
  const int wi = blockIdx.z;   // 0=Q 1=K 2=V
  const unsigned short* Xb = ws + (WS_X >> 1);
  const unsigned short* Wb = ws + (WS_W >> 1);

  short8 af[2][8];
#pragma unroll
  for (int mt = 0; mt < 2; ++mt)
#pragma unroll
    for (int kc = 0; kc < 8; ++kc)
      af[mt][kc] = *(const short8*)(Xb + ((size_t)((n * 128 + tt2 * 2 + mt) * 8 + kc) * 512 + lane * 8));

  f32x4 acc[2][4];
#pragma unroll
  for (int mt = 0; mt < 2; ++mt)
#pragma unroll
    for (int nt = 0; nt < 4; ++nt) {
      f32x4 z = {0.f, 0.f, 0.f, 0.f};
      acc[mt][nt] = z;
    }

#pragma unroll
  for (int kc = 0; kc < 8; ++kc) {
    short8 bf[4];
#pragma unroll
    for (int nt = 0; nt < 4; ++nt)
      bf[nt] = *(const short8*)(Wb + ((size_t)((wi * 16 + w * 4 + nt) * 8 + kc) * 512 + lane * 8));
#pragma unroll
    for (int mt = 0; mt < 2; ++mt)
#pragma unroll
      for (int nt = 0; nt < 4; ++nt)
        acc[mt][nt] = __builtin_amdgcn_mfma_f32_16x16x32_bf16(af[mt][kc], bf[nt], acc[mt][nt], 0, 0, 0);
  }

  // C layout: value (mt,nt,r) at lane(lc,lq) is element (t = tt2*32+mt*16+lq*4+r,
  //                                                      o = w*64+nt*16+lc)
  if (wi < 2) {
    unsigned short* ep = eps[w];
#pragma unroll
    for (int mt = 0; mt < 2; ++mt)
#pragma unroll
      for (int nt = 0; nt < 4; ++nt) {
        const int m2 = ((nt & 1) << 1) | (lc >> 3);
        const int base = ((mt * 2 + (nt >> 1)) << 9) + (m2 << 7) + (lq << 5) + (lc & 7);
#pragma unroll
        for (int r = 0; r < 4; ++r)
          ep[base + ((r ^ m2) << 3)] = f2bf(acc[mt][nt][r]);
      }
    const int swzl = lane ^ (lane >> 4);
    unsigned short* dst = ws + ((wi == 0) ? (WS_Q >> 1) : (WS_K >> 1));
#pragma unroll
    for (int rl = 0; rl < 4; ++rl) {
      int4 v = *(const int4*)(ep + (rl << 9) + swzl * 8);
      const int mt = rl >> 1, hh = rl & 1;
      const int nh = n * 8 + w * 2 + hh;
      const int ttg = tt2 * 2 + mt;
      *(int4*)(dst + ((size_t)(nh * 128 + ttg) * 64 + lane) * 8) = v;
    }
  } else {
    // V: target [nh][kb][dt][sbp][lane][half*4+j] -- lane mapping is IDENTITY.
    const int kb = tt2 >> 1, sbp = tt2 & 1;
#pragma unroll
    for (int nt = 0; nt < 4; ++nt) {
      const int nh = n * 8 + w * 2 + (nt >> 1);
      const int dt = nt & 1;
      alignas(16) unsigned short tmp[8];
#pragma unroll
      for (int mt = 0; mt < 2; ++mt)
#pragma unroll
        for (int r = 0; r < 4; ++r) tmp[mt * 4 + r] = f2bf(acc[mt][nt][r]);
      unsigned short* dstv = ws + (WS_V >> 1) +
          ((size_t)((((nh * 32 + kb) * 2 + dt) * 2 + sbp)) * 64 + lane) * 8;
      *(int4*)dstv = *(const int4*)tmp;
    }
  }
}

// ------ fused flash attention: split-K, barrier-free, XCD-pinned chunks -------
// 1D grid, blockIdx.x = qx*CH + c, chunk id c = ks*32+nh. linear%8 = nh&7 ->
// all blocks touching head nh land on one XCD. Waves fully independent (no
// LDS, no barriers). Each wave owns 64 q rows (4 q-frags). 2 waves/SIMD;
// register pipeline (K reload-in-place, V ping-pong) covers L2 latency.
// __launch_bounds__(128,2): VGPR cap 256, no spills.
template <int KS>
__global__ __launch_bounds__(128, 2) void attn_kernel(
    const unsigned short* __restrict__ ws, float* __restrict__ out,
    unsigned short* __restrict__ opart, float* __restrict__ lpart) {
  const int tid = threadIdx.x;
  const int lane = tid & 63, wv = tid >> 6;
  const int lc = lane & 15, quad = lane >> 4;
  constexpr int CH = 32 * KS;
  const int c = blockIdx.x & (CH - 1);
  const int qx = blockIdx.x / CH;   // 0..15
  const int nh = c & 31;            // chunk -> XCD pin: nh&7
  const int ks = c >> 5;            // 0..KS-1
  const int qw = qx * 2 + wv;       // 0..31 -> q rows qw*64 .. +63
  constexpr int NKB = 32 / KS;      // kb blocks of 64 keys each
  const int kb0 = ks * NKB;

  const unsigned short* Qw = ws + (WS_Q >> 1) + ((size_t)(nh * 128 + qw * 4)) * 512;
  const unsigned short* Kb = ws + (WS_K >> 1) + (size_t)nh * 65536;
  const unsigned short* Vb = ws + (WS_V >> 1) + (size_t)nh * 65536;

  // Q B-frags (16x16x32): n=query on lane&15, k=dk on quad*8+j. Loaded once.
  short8 qf[4];
#pragma unroll
  for (int mt = 0; mt < 4; ++mt)
    qf[mt] = *(const short8*)(Qw + mt * 512 + lane * 8);

  f32x4 acc[4][2];
#pragma unroll
  for (int mt = 0; mt < 4; ++mt)
#pragma unroll
    for (int dt = 0; dt < 2; ++dt) {
      f32x4 z = {0.f, 0.f, 0.f, 0.f};
      acc[mt][dt] = z;
    }
  float lsum[4] = {0.f, 0.f, 0.f, 0.f};

  auto load_k = [&](short8 kf[4], int kb) {
    const unsigned short* kp = Kb + (size_t)kb * 2048 + lane * 8;
#pragma unroll
    for (int sb = 0; sb < 4; ++sb) kf[sb] = *(const short8*)(kp + sb * 512);
  };
  auto load_v = [&](short8 vv[4], int kb) {
    const unsigned short* vp = Vb + (size_t)kb * 2048 + lane * 8;
#pragma unroll
    for (int u = 0; u < 4; ++u) vv[u] = *(const short8*)(vp + u * 512);
  };

  // S^T = K * Q^T via 16x16x32: A=K-frag (m=key), B=Q-frag (n=query).
  // C-layout of S^T (col=query, row=key quad*4+r) == A-frag layout of 16x16x16.
  // st consumed per-sb immediately -> only 4 f32 of st live at a time.
  auto do_qk = [&](const short8 kf[4], short4v pf[4][4]) {
#pragma unroll
    for (int mt = 0; mt < 4; ++mt)
#pragma unroll
      for (int sb = 0; sb < 4; ++sb) {
        f32x4 z = {0.f, 0.f, 0.f, 0.f};
        f32x4 st = __builtin_amdgcn_mfma_f32_16x16x32_bf16(kf[sb], qf[mt], z, 0, 0, 0);
        float p0 = __builtin_amdgcn_exp2f(st[0]);
        float p1 = __builtin_amdgcn_exp2f(st[1]);
        float p2 = __builtin_amdgcn_exp2f(st[2]);
        float p3 = __builtin_amdgcn_exp2f(st[3]);
        lsum[mt] += (p0 + p1) + (p2 + p3);
        int2 pi;
        pi.x = pack_bf16rn(p0, p1);
        pi.y = pack_bf16rn(p2, p3);
        pf[mt][sb] = __builtin_bit_cast(short4v, pi);
      }
  };

  // O += P * V via 16x16x16 (V B-frag prepacked: n=d on lane&15, k=key)
  auto do_pv = [&](const short8 vv[4], const short4v pf[4][4]) {
    short4v vf[4][2];
#pragma unroll
    for (int dt = 0; dt < 2; ++dt)
#pragma unroll
      for (int sbp = 0; sbp < 2; ++sbp) {
        short8 t = vv[dt * 2 + sbp];
        vf[sbp * 2 + 0][dt] = __builtin_shufflevector(t, t, 0, 1, 2, 3);
        vf[sbp * 2 + 1][dt] = __builtin_shufflevector(t, t, 4, 5, 6, 7);
      }
#pragma unroll
    for (int sb = 0; sb < 4; ++sb)
#pragma unroll
      for (int mt = 0; mt < 4; ++mt) {
        acc[mt][0] = __builtin_amdgcn_mfma_f32_16x16x16bf16_1k(pf[mt][sb], vf[sb][0], acc[mt][0], 0, 0, 0);
        acc[mt][1] = __builtin_amdgcn_mfma_f32_16x16x16bf16_1k(pf[mt][sb], vf[sb][1], acc[mt][1], 0, 0, 0);
      }
  };

  // Software pipeline, 2 kb per loop iteration, last pair peeled.
  // K reloaded in-place right after its QK consumes it (gap = one PV phase);
  // V ping-pong (vA/vB, named -> stays in registers) with full-iter distance.
  short8 kf[4], vA[4], vB[4];
  load_k(kf, kb0);
  load_v(vA, kb0);
  int kb = kb0;
  for (; kb < kb0 + NKB - 2; kb += 2) {
    short4v pfA[4][4];
    do_qk(kf, pfA);
    load_k(kf, kb + 1);
    load_v(vB, kb + 1);
    do_pv(vA, pfA);
    short4v pfB[4][4];
    do_qk(kf, pfB);
    load_k(kf, kb + 2);
    load_v(vA, kb + 2);
    do_pv(vB, pfB);
  }
  {
    short4v pfA[4][4];
    do_qk(kf, pfA);
    load_k(kf, kb + 1);
    load_v(vB, kb + 1);
    do_pv(vA, pfA);
    short4v pfB[4][4];
    do_qk(kf, pfB);
    do_pv(vB, pfB);
  }

  // finish row sums across quads
#pragma unroll
  for (int mt = 0; mt < 4; ++mt) {
    lsum[mt] += __shfl_xor(lsum[mt], 16);
    lsum[mt] += __shfl_xor(lsum[mt], 32);
  }

  if constexpr (KS == 1) {
    // normalize + direct store. acc C-layout: col=lc=d, row=quad*4+r=q (+mt*16)
    const int chbase = (nh >> 3) * 256 + (nh & 7) * 32;
#pragma unroll
    for (int mt = 0; mt < 4; ++mt) {
      float is[4];
#pragma unroll
      for (int r = 0; r < 4; ++r) is[r] = 1.0f / __shfl(lsum[mt], quad * 4 + r);
      const int tb = qw * 64 + mt * 16 + quad * 4;
#pragma unroll
      for (int dt = 0; dt < 2; ++dt) {
        f32x4 ov;
#pragma unroll
        for (int r = 0; r < 4; ++r) ov[r] = acc[mt][dt][r] * is[r];
        *(f32x4*)(out + (size_t)(chbase + dt * 16 + lc) * 2048 + tb) = ov;
      }
    }
  } else {
    // store UNnormalized bf16 partials (halved traffic); finalize combines.
    const size_t ob = (size_t)(ks * 32 + nh) * 32 * 2048;  // shorts
#pragma unroll
    for (int mt = 0; mt < 4; ++mt) {
      const int tb = qw * 64 + mt * 16 + quad * 4;
#pragma unroll
      for (int dt = 0; dt < 2; ++dt) {
        int2 pi;
        pi.x = pack_bf16rn(acc[mt][dt][0], acc[mt][dt][1]);
        pi.y = pack_bf16rn(acc[mt][dt][2], acc[mt][dt][3]);
        *(int2*)(opart + ob + (size_t)(dt * 16 + lc) * 2048 + tb) = pi;
      }
      if (quad == 0)
        lpart[(size_t)(ks * 32 + nh) * 2048 + qw * 64 + mt * 16 + lc] = lsum[mt];
    }
  }
}

// ---------------- finalize: out = (sum_ks O_part) / (sum_ks l_part) -----------
template <int KS>
__global__ __launch_bounds__(256) void finalize_kernel(
    const unsigned short* __restrict__ opart, const float* __restrict__ lpart,
    float* __restrict__ out) {
  const int f = blockIdx.x * 256 + threadIdx.x;  // float4 index, 0..524287
  const int t4 = f & 511;
  const int c = f >> 9;  // n*256 + ch
  const int n = c >> 8, ch = c & 255;
  const int nh = n * 8 + (ch >> 5), d = ch & 31;
  float o[4] = {0.f, 0.f, 0.f, 0.f};
  float l[4] = {0.f, 0.f, 0.f, 0.f};
#pragma unroll
  for (int ks = 0; ks < KS; ++ks) {
    const short4v ov = *(const short4v*)(opart + ((size_t)(ks * 32 + nh) * 32 + d) * 2048 + t4 * 4);
    const float4 lv = *(const float4*)(lpart + (size_t)(ks * 32 + nh) * 2048 + t4 * 4);
#pragma unroll
    for (int i = 0; i < 4; ++i) {
      const unsigned int u = ((unsigned int)(unsigned short)ov[i]) << 16;
      o[i] += __builtin_bit_cast(float, u);
    }
    l[0] += lv.x; l[1] += lv.y; l[2] += lv.z; l[3] += lv.w;
  }
  float4 r;
  r.x = o[0] / l[0]; r.y = o[1] / l[1]; r.z = o[2] / l[2]; r.w = o[3] / l[3];
  *(float4*)(out + (size_t)f * 4) = r;
}

extern "C" void kernel_launch(void* const* d_in, const int* in_sizes, int n_in,
                              void* d_out, int out_size, void* d_ws, size_t ws_size,
                              hipStream_t stream) {
  const float* x = (const float*)d_in[0];
  const float* Wq = (const float*)d_in[1];
  const float* Wk = (const float*)d_in[2];
  const float* Wv = (const float*)d_in[3];
  unsigned short* ws = (unsigned short*)d_ws;
  float* out = (float*)d_out;
  (void)in_sizes; (void)n_in; (void)out_size;

  pack_kernel<<<1120, 256, 0, stream>>>(x, Wq, Wk, Wv, ws);
  proj_kernel<<<dim3(64, 4, 3), 256, 0, stream>>>(ws);

  char* wsb = (char*)d_ws;
  unsigned short* opart = (unsigned short*)(wsb + WS_OP);
  if (ws_size >= ((size_t)30u << 20)) {
    float* lpart = (float*)(wsb + WS_OP + ((size_t)2 * 4u << 20));
    // PROBE: attn launched 3x (idempotent). dur_us = base + 2*T_attn.
    attn_kernel<2><<<1024, 128, 0, stream>>>(ws, out, opart, lpart);
    attn_kernel<2><<<1024, 128, 0, stream>>>(ws, out, opart, lpart);
    attn_kernel<2><<<1024, 128, 0, stream>>>(ws, out, opart, lpart);
    finalize_kernel<2><<<2048, 256, 0, stream>>>(opart, lpart, out);
  } else {
    attn_kernel<1><<<512, 128, 0, stream>>>(ws, out, nullptr, nullptr);
  }
}

// Round 6
// 112.969 us; speedup vs baseline: 1.4263x; 1.4263x over previous
//
#include <hip/hip_runtime.h>

// MultiHeadAttn1D: N=4, C=256, T=2048, H=8, dk=dv=32.
// ws layout (bytes):
//   [0   , 4Mi ) Q_ws  bf16 B-frag (16x16x32): [nh(32)][qtile(128)][lane(64)][8]
//                lane=(t&15)+16*(d>>3), j=d&7   (Q pre-scaled by log2e/sqrt(32))
//   [4Mi , 8Mi ) K_ws  bf16 A-frag (16x16x32): [nh][ktile(128)][lane][8]
//   [8Mi ,12Mi ) V_ws  bf16 B-frag (16x16x16): [nh][kb(32)][dt(2)][sbp(2)][lane][8]
//   [12Mi,16Mi ) Xb    bf16 A-frag x: [n(4)][tt(128)][kc(8)][lane][8]
//   [16Mi,16.4Mi) Wb   bf16 B-frag W: [wi(3)][ot(16)][kc(8)][lane][8]
//   [20Mi, +KS*4Mi)        O_part bf16 [ks][nh][d(32)][t(2048)]    (KS>1 only)
//   [20Mi+KS*4Mi, +KS*256Ki) l_part fp32 [ks][nh][t(2048)]         (KS>1 only)
//
// R10 = R9 with the NaN suspect removed: the v_cvt_pk_bf16_f32 inline asm is
// replaced by the proven pack_bf16rn (if cvt_pk's dst semantics leave the
// high 16 bits stale, garbage bf16 NaN patterns propagate through PV MFMA ->
// NaN output, matching the observed failure; the guide's m240 also measured
// hand-written cvt_pk as slower anyway). All other R9 elements kept:
//   - lsum via ones-column MFMA (rowsum on idle MFMA pipe, layout-independent)
//   - per-sb streaming QK->exp->pack->PV (pf live 32->8 regs)
//   - K reload per-sb in place, V staggered in-place reload (prefetch dist 1)
//   - __launch_bounds__(128,3) + KS=4 grid -> 3 waves/SIMD.

typedef float f32x4 __attribute__((ext_vector_type(4)));
typedef short short8 __attribute__((ext_vector_type(8)));
typedef short short4v __attribute__((ext_vector_type(4)));

#define WS_Q 0u
#define WS_K (4u << 20)
#define WS_V (8u << 20)
#define WS_X (12u << 20)
#define WS_W (16u << 20)
#define WS_OP (20u << 20)

__device__ __forceinline__ unsigned short f2bf(float f) {
  unsigned int u = __builtin_bit_cast(unsigned int, f);
  u += 0x7FFFu + ((u >> 16) & 1u);
  return (unsigned short)(u >> 16);
}

// pack two floats to bf16 into one dword: [bf(a) | bf(b)<<16]  (proven R0-R3)
__device__ __forceinline__ int pack_bf16rn(float a, float b) {
  unsigned int ua = __builtin_bit_cast(unsigned int, a) + 0x8000u;
  unsigned int ub = __builtin_bit_cast(unsigned int, b) + 0x8000u;
  return __builtin_amdgcn_perm(ub, ua, 0x07060302);
}

// ---------------- pack: x -> Xb (bf16 A-frags), W -> Wb (bf16 B-frags) ---------
__global__ __launch_bounds__(256) void pack_kernel(
    const float* __restrict__ x, const float* __restrict__ Wq,
    const float* __restrict__ Wk, const float* __restrict__ Wv,
    unsigned short* __restrict__ ws) {
  const int tid = threadIdx.x;
  const int lane = tid & 63;
  const int wv = tid >> 6;
  const int lc = lane & 15, lq = lane >> 4;
  const int b = blockIdx.x;
  alignas(16) unsigned short tmp[8];
  if (b < 1024) {
    const int r = b * 4 + wv;  // 0..4095 = (n,tt,kc)
    const int kc = r & 7, tt = (r >> 3) & 127, n = r >> 10;
    const int t = tt * 16 + lc;
    const int c0 = kc * 32 + lq * 8;
    const float* src = x + (size_t)(n * 256 + c0) * 2048 + t;
#pragma unroll
    for (int j = 0; j < 8; ++j) tmp[j] = f2bf(src[(size_t)j * 2048]);
    unsigned short* dst = ws + (WS_X >> 1) + (size_t)r * 512 + lane * 8;
    *(int4*)dst = *(const int4*)tmp;
  } else {
    const int r = (b - 1024) * 4 + wv;  // 0..383 = (wi,ot,kc)
    const int kc = r & 7, ot = (r >> 3) & 15, wi = r >> 7;
    const float* W = (wi == 0) ? Wq : (wi == 1) ? Wk : Wv;
    const float scale = (wi == 0) ? 0.25503492f : 1.0f;  // log2(e)/sqrt(32)
    const int o = ot * 16 + lc;
    const int c0 = kc * 32 + lq * 8;
    const float* src = W + o * 256 + c0;
#pragma unroll
    for (int j = 0; j < 8; ++j) tmp[j] = f2bf(src[j] * scale);
    unsigned short* dst = ws + (WS_W >> 1) + (size_t)r * 512 + lane * 8;
    *(int4*)dst = *(const int4*)tmp;
  }
}

// ---------------- projection GEMM: Q/K/V = W * x, frag-packed outputs ----------
__global__ __launch_bounds__(256) void proj_kernel(unsigned short* __restrict__ ws) {
  __shared__ unsigned short eps[4][2048];  // per-wave 4KB swizzle buffer (Q/K only)
  const int tid = threadIdx.x, lane = tid & 63, w = tid >> 6;
  const int lc = lane & 15, lq = lane >> 4;
  const int tt2 = blockIdx.x;  // 0..63 : t-range of 32
  const int n = blockIdx.y;    // 0..3
  const int wi = blockIdx.z;   // 0=Q 1=K 2=V
  const unsigned short* Xb = ws + (WS_X >> 1);
  const unsigned short* Wb = ws + (WS_W >> 1);

  short8 af[2][8];
#pragma unroll
  for (int mt = 0; mt < 2; ++mt)
#pragma unroll
    for (int kc = 0; kc < 8; ++kc)
      af[mt][kc] = *(const short8*)(Xb + ((size_t)((n * 128 + tt2 * 2 + mt) * 8 + kc) * 512 + lane * 8));

  f32x4 acc[2][4];
#pragma unroll
  for (int mt = 0; mt < 2; ++mt)
#pragma unroll
    for (int nt = 0; nt < 4; ++nt) {
      f32x4 z = {0.f, 0.f, 0.f, 0.f};
      acc[mt][nt] = z;
    }

#pragma unroll
  for (int kc = 0; kc < 8; ++kc) {
    short8 bf[4];
#pragma unroll
    for (int nt = 0; nt < 4; ++nt)
      bf[nt] = *(const short8*)(Wb + ((size_t)((wi * 16 + w * 4 + nt) * 8 + kc) * 512 + lane * 8));
#pragma unroll
    for (int mt = 0; mt < 2; ++mt)
#pragma unroll
      for (int nt = 0; nt < 4; ++nt)
        acc[mt][nt] = __builtin_amdgcn_mfma_f32_16x16x32_bf16(af[mt][kc], bf[nt], acc[mt][nt], 0, 0, 0);
  }

  // C layout: value (mt,nt,r) at lane(lc,lq) is element (t = tt2*32+mt*16+lq*4+r,
  //                                                      o = w*64+nt*16+lc)
  if (wi < 2) {
    unsigned short* ep = eps[w];
#pragma unroll
    for (int mt = 0; mt < 2; ++mt)
#pragma unroll
      for (int nt = 0; nt < 4; ++nt) {
        const int m2 = ((nt & 1) << 1) | (lc >> 3);
        const int base = ((mt * 2 + (nt >> 1)) << 9) + (m2 << 7) + (lq << 5) + (lc & 7);
#pragma unroll
        for (int r = 0; r < 4; ++r)
          ep[base + ((r ^ m2) << 3)] = f2bf(acc[mt][nt][r]);
      }
    const int swzl = lane ^ (lane >> 4);
    unsigned short* dst = ws + ((wi == 0) ? (WS_Q >> 1) : (WS_K >> 1));
#pragma unroll
    for (int rl = 0; rl < 4; ++rl) {
      int4 v = *(const int4*)(ep + (rl << 9) + swzl * 8);
      const int mt = rl >> 1, hh = rl & 1;
      const int nh = n * 8 + w * 2 + hh;
      const int ttg = tt2 * 2 + mt;
      *(int4*)(dst + ((size_t)(nh * 128 + ttg) * 64 + lane) * 8) = v;
    }
  } else {
    // V: target [nh][kb][dt][sbp][lane][half*4+j] -- lane mapping is IDENTITY.
    const int kb = tt2 >> 1, sbp = tt2 & 1;
#pragma unroll
    for (int nt = 0; nt < 4; ++nt) {
      const int nh = n * 8 + w * 2 + (nt >> 1);
      const int dt = nt & 1;
      alignas(16) unsigned short tmp[8];
#pragma unroll
      for (int mt = 0; mt < 2; ++mt)
#pragma unroll
        for (int r = 0; r < 4; ++r) tmp[mt * 4 + r] = f2bf(acc[mt][nt][r]);
      unsigned short* dstv = ws + (WS_V >> 1) +
          ((size_t)((((nh * 32 + kb) * 2 + dt) * 2 + sbp)) * 64 + lane) * 8;
      *(int4*)dstv = *(const int4*)tmp;
    }
  }
}

// ------ fused flash attention: split-K, barrier-free, XCD-pinned chunks -------
// 1D grid, blockIdx.x = qx*CH + c, chunk id c = ks*32+nh. linear%8 = nh&7 ->
// all blocks touching head nh land on one XCD. Waves fully independent (no
// LDS, no barriers). Each wave: 64 q rows x NKB kb-blocks of 64 keys.
// Per-sb streaming: 16-key slice = {4 QK MFMA -> 16 exp2 -> 8 pack ->
// 4 lsum-MFMA (ones B-frag) -> 8 PV MFMA}. K reloaded per-sb in place
// (3/4-kb prefetch distance); V reloaded in place staggered (sb1/sb3).
// __launch_bounds__(128,3): 168-reg cap, 3 waves/SIMD.
template <int KS>
__global__ __launch_bounds__(128, 3) void attn_kernel(
    const unsigned short* __restrict__ ws, float* __restrict__ out,
    unsigned short* __restrict__ opart, float* __restrict__ lpart) {
  const int tid = threadIdx.x;
  const int lane = tid & 63, wv = tid >> 6;
  const int lc = lane & 15, quad = lane >> 4;
  constexpr int CH = 32 * KS;
  const int c = blockIdx.x & (CH - 1);
  const int qx = blockIdx.x / CH;   // 0..15
  const int nh = c & 31;            // chunk -> XCD pin: nh&7
  const int ks = c >> 5;            // 0..KS-1
  const int qw = qx * 2 + wv;       // 0..31 -> q rows qw*64 .. +63
  constexpr int NKB = 32 / KS;      // kb blocks of 64 keys each
  const int kb0 = ks * NKB;

  const unsigned short* Qw = ws + (WS_Q >> 1) + ((size_t)(nh * 128 + qw * 4)) * 512;
  const unsigned short* Kb = ws + (WS_K >> 1) + (size_t)nh * 65536;
  const unsigned short* Vb = ws + (WS_V >> 1) + (size_t)nh * 65536;

  // Q B-frags (16x16x32): n=query on lane&15, k=dk on quad*8+j. Loaded once.
  short8 qf[4];
#pragma unroll
  for (int mt = 0; mt < 4; ++mt)
    qf[mt] = *(const short8*)(Qw + mt * 512 + lane * 8);

  f32x4 acc[4][2];
  f32x4 lsum_acc[4];
#pragma unroll
  for (int mt = 0; mt < 4; ++mt) {
    f32x4 z = {0.f, 0.f, 0.f, 0.f};
    acc[mt][0] = z;
    acc[mt][1] = z;
    lsum_acc[mt] = z;
  }
  // B-frag of all-ones bf16: D = P * ones -> every column = rowsum(P).
  const short4v onesf = {(short)0x3F80, (short)0x3F80, (short)0x3F80, (short)0x3F80};

  short8 kf[4], vv[4];
  {
    const unsigned short* kp = Kb + (size_t)kb0 * 2048 + lane * 8;
    const unsigned short* vp = Vb + (size_t)kb0 * 2048 + lane * 8;
#pragma unroll
    for (int u = 0; u < 4; ++u) kf[u] = *(const short8*)(kp + u * 512);
#pragma unroll
    for (int u = 0; u < 4; ++u) vv[u] = *(const short8*)(vp + u * 512);
  }

#pragma unroll 2
  for (int kb = kb0; kb < kb0 + NKB; ++kb) {
    // prefetch pointers for next kb (last iter reads 1 block past the chunk:
    // stays inside ws regions, values never consumed)
    const unsigned short* nkp = Kb + (size_t)(kb + 1) * 2048 + lane * 8;
    const unsigned short* nvp = Vb + (size_t)(kb + 1) * 2048 + lane * 8;
#pragma unroll
    for (int sb = 0; sb < 4; ++sb) {
      // V B-frags for this 16-key slice: sbp = sb>>1, half = sb&1
      const short8 t0 = vv[(sb >> 1)];      // dt=0
      const short8 t1 = vv[2 + (sb >> 1)];  // dt=1
      short4v vf0, vf1;
      if (sb & 1) {
        vf0 = __builtin_shufflevector(t0, t0, 4, 5, 6, 7);
        vf1 = __builtin_shufflevector(t1, t1, 4, 5, 6, 7);
      } else {
        vf0 = __builtin_shufflevector(t0, t0, 0, 1, 2, 3);
        vf1 = __builtin_shufflevector(t1, t1, 0, 1, 2, 3);
      }
      // S^T = K * Q^T (A=K m=key, B=Q n=query); C-layout == A-frag of 16x16x16
      f32x4 st[4];
#pragma unroll
      for (int mt = 0; mt < 4; ++mt) {
        f32x4 z = {0.f, 0.f, 0.f, 0.f};
        st[mt] = __builtin_amdgcn_mfma_f32_16x16x32_bf16(kf[sb], qf[mt], z, 0, 0, 0);
      }
      // kf[sb] dead now -> reload for next kb (3/4-kb prefetch distance)
      kf[sb] = *(const short8*)(nkp + sb * 512);
      // staggered in-place V reload: vv[0],vv[2] dead after sb=1; vv[1],vv[3] after sb=3
      if (sb == 1) {
        vv[0] = *(const short8*)(nvp + 0 * 512);
        vv[2] = *(const short8*)(nvp + 2 * 512);
      }
      if (sb == 3) {
        vv[1] = *(const short8*)(nvp + 1 * 512);
        vv[3] = *(const short8*)(nvp + 3 * 512);
      }
#pragma unroll
      for (int mt = 0; mt < 4; ++mt) {
        const float p0 = __builtin_amdgcn_exp2f(st[mt][0]);
        const float p1 = __builtin_amdgcn_exp2f(st[mt][1]);
        const float p2 = __builtin_amdgcn_exp2f(st[mt][2]);
        const float p3 = __builtin_amdgcn_exp2f(st[mt][3]);
        int2 pi;
        pi.x = pack_bf16rn(p0, p1);
        pi.y = pack_bf16rn(p2, p3);
        const short4v pf = __builtin_bit_cast(short4v, pi);
        // rowsum on the MFMA pipe; denominator == sum of the bf16 p's used in PV
        lsum_acc[mt] = __builtin_amdgcn_mfma_f32_16x16x16bf16_1k(pf, onesf, lsum_acc[mt], 0, 0, 0);
        acc[mt][0] = __builtin_amdgcn_mfma_f32_16x16x16bf16_1k(pf, vf0, acc[mt][0], 0, 0, 0);
        acc[mt][1] = __builtin_amdgcn_mfma_f32_16x16x16bf16_1k(pf, vf1, acc[mt][1], 0, 0, 0);
      }
    }
  }

  // lsum_acc C-layout: col=lc (all 16 columns identical), row=quad*4+r --
  // exactly matches acc rows: per-lane elementwise normalization, no shuffles.
  if constexpr (KS == 1) {
    const int chbase = (nh >> 3) * 256 + (nh & 7) * 32;
#pragma unroll
    for (int mt = 0; mt < 4; ++mt) {
      f32x4 is;
#pragma unroll
      for (int r = 0; r < 4; ++r) is[r] = 1.0f / lsum_acc[mt][r];
      const int tb = qw * 64 + mt * 16 + quad * 4;
#pragma unroll
      for (int dt = 0; dt < 2; ++dt) {
        f32x4 ov;
#pragma unroll
        for (int r = 0; r < 4; ++r) ov[r] = acc[mt][dt][r] * is[r];
        *(f32x4*)(out + (size_t)(chbase + dt * 16 + lc) * 2048 + tb) = ov;
      }
    }
  } else {
    // store UNnormalized bf16 partials (halved traffic); finalize combines.
    const size_t ob = (size_t)(ks * 32 + nh) * 32 * 2048;  // shorts
#pragma unroll
    for (int mt = 0; mt < 4; ++mt) {
      const int tb = qw * 64 + mt * 16 + quad * 4;
#pragma unroll
      for (int dt = 0; dt < 2; ++dt) {
        int2 pi;
        pi.x = pack_bf16rn(acc[mt][dt][0], acc[mt][dt][1]);
        pi.y = pack_bf16rn(acc[mt][dt][2], acc[mt][dt][3]);
        *(int2*)(opart + ob + (size_t)(dt * 16 + lc) * 2048 + tb) = pi;
      }
      if (lc == 0)
        *(f32x4*)(lpart + (size_t)(ks * 32 + nh) * 2048 + qw * 64 + mt * 16 + quad * 4) = lsum_acc[mt];
    }
  }
}

// ---------------- finalize: out = (sum_ks O_part) / (sum_ks l_part) -----------
template <int KS>
__global__ __launch_bounds__(256) void finalize_kernel(
    const unsigned short* __restrict__ opart, const float* __restrict__ lpart,
    float* __restrict__ out) {
  const int f = blockIdx.x * 256 + threadIdx.x;  // float4 index, 0..524287
  const int t4 = f & 511;
  const int c = f >> 9;  // n*256 + ch
  const int n = c >> 8, ch = c & 255;
  const int nh = n * 8 + (ch >> 5), d = ch & 31;
  float o[4] = {0.f, 0.f, 0.f, 0.f};
  float l[4] = {0.f, 0.f, 0.f, 0.f};
#pragma unroll
  for (int ks = 0; ks < KS; ++ks) {
    const short4v ov = *(const short4v*)(opart + ((size_t)(ks * 32 + nh) * 32 + d) * 2048 + t4 * 4);
    const float4 lv = *(const float4*)(lpart + (size_t)(ks * 32 + nh) * 2048 + t4 * 4);
#pragma unroll
    for (int i = 0; i < 4; ++i) {
      const unsigned int u = ((unsigned int)(unsigned short)ov[i]) << 16;
      o[i] += __builtin_bit_cast(float, u);
    }
    l[0] += lv.x; l[1] += lv.y; l[2] += lv.z; l[3] += lv.w;
  }
  float4 r;
  r.x = o[0] / l[0]; r.y = o[1] / l[1]; r.z = o[2] / l[2]; r.w = o[3] / l[3];
  *(float4*)(out + (size_t)f * 4) = r;
}

extern "C" void kernel_launch(void* const* d_in, const int* in_sizes, int n_in,
                              void* d_out, int out_size, void* d_ws, size_t ws_size,
                              hipStream_t stream) {
  const float* x = (const float*)d_in[0];
  const float* Wq = (const float*)d_in[1];
  const float* Wk = (const float*)d_in[2];
  const float* Wv = (const float*)d_in[3];
  unsigned short* ws = (unsigned short*)d_ws;
  float* out = (float*)d_out;
  (void)in_sizes; (void)n_in; (void)out_size;

  pack_kernel<<<1120, 256, 0, stream>>>(x, Wq, Wk, Wv, ws);
  proj_kernel<<<dim3(64, 4, 3), 256, 0, stream>>>(ws);

  char* wsb = (char*)d_ws;
  unsigned short* opart = (unsigned short*)(wsb + WS_OP);
  if (ws_size >= ((size_t)41u << 20)) {
    // KS=4: 16 qx-groups x 128 chunks = 2048 blocks x 2 waves = 4096 waves
    // -> 3 waves/SIMD resident; 8 kb-blocks per wave.
    float* lpart = (float*)(wsb + WS_OP + ((size_t)4 * 4u << 20));
    attn_kernel<4><<<2048, 128, 0, stream>>>(ws, out, opart, lpart);
    finalize_kernel<4><<<2048, 256, 0, stream>>>(opart, lpart, out);
  } else if (ws_size >= ((size_t)30u << 20)) {
    float* lpart = (float*)(wsb + WS_OP + ((size_t)2 * 4u << 20));
    attn_kernel<2><<<1024, 128, 0, stream>>>(ws, out, opart, lpart);
    finalize_kernel<2><<<2048, 256, 0, stream>>>(opart, lpart, out);
  } else {
    attn_kernel<1><<<512, 128, 0, stream>>>(ws, out, nullptr, nullptr);
  }
}

// Round 7
// 112.032 us; speedup vs baseline: 1.4382x; 1.0084x over previous
//
#include <hip/hip_runtime.h>

// MultiHeadAttn1D: N=4, C=256, T=2048, H=8, dk=dv=32.
// ws layout (bytes):
//   [0   , 4Mi ) Q_ws  bf16 B-frag (16x16x32): [nh(32)][qtile(128)][lane(64)][8]
//                lane=(t&15)+16*(d>>3), j=d&7   (Q pre-scaled by log2e/sqrt(32))
//   [4Mi , 8Mi ) K_ws  bf16 A-frag (16x16x32): [nh][ktile(128)][lane][8]
//   [8Mi ,12Mi ) V_ws  bf16 B-frag (16x16x16): [nh][kb(32)][dt(2)][sbp(2)][lane][8]
//   [12Mi,16Mi ) Xb    bf16 A-frag x: [n(4)][tt(128)][kc(8)][lane][8]
//   [16Mi,16.4Mi) Wb   bf16 B-frag W: [wi(3)][ot(16)][kc(8)][lane][8]
//
// R11 (this round): KS=1 only -- finalize kernel DELETED (3 dispatches total).
// R4 probe + R6 budget audit: fill 43 + attn 25.7 + pack 3 + proj 6 +
// finalize 4.5 + ~26us of inter-dispatch gaps ~= 110. Three attn structures
// (R1/R3/R10) all ~25.7us -> attn is at its trans-pipe (v_exp_f32, 134M
// scores) floor; dispatch count is the cheapest remaining lever. 32q/wave
// KS=1 keeps 2048 waves (2/SIMD, same TLP as R3) while letting attn
// normalize in-register (lsum_acc rows == acc rows, per-lane multiply) and
// write f32 out directly -- drops finalize + its gap + 36MB opart traffic.
// attn internals = R10's passing structure (per-sb streaming, lsum via
// ones-MFMA, staggered in-place K/V reloads).

typedef float f32x4 __attribute__((ext_vector_type(4)));
typedef short short8 __attribute__((ext_vector_type(8)));
typedef short short4v __attribute__((ext_vector_type(4)));

#define WS_Q 0u
#define WS_K (4u << 20)
#define WS_V (8u << 20)
#define WS_X (12u << 20)
#define WS_W (16u << 20)

__device__ __forceinline__ unsigned short f2bf(float f) {
  unsigned int u = __builtin_bit_cast(unsigned int, f);
  u += 0x7FFFu + ((u >> 16) & 1u);
  return (unsigned short)(u >> 16);
}

// pack two floats to bf16 into one dword: [bf(a) | bf(b)<<16]  (proven R0-R10)
__device__ __forceinline__ int pack_bf16rn(float a, float b) {
  unsigned int ua = __builtin_bit_cast(unsigned int, a) + 0x8000u;
  unsigned int ub = __builtin_bit_cast(unsigned int, b) + 0x8000u;
  return __builtin_amdgcn_perm(ub, ua, 0x07060302);
}

// ---------------- pack: x -> Xb (bf16 A-frags), W -> Wb (bf16 B-frags) ---------
__global__ __launch_bounds__(256) void pack_kernel(
    const float* __restrict__ x, const float* __restrict__ Wq,
    const float* __restrict__ Wk, const float* __restrict__ Wv,
    unsigned short* __restrict__ ws) {
  const int tid = threadIdx.x;
  const int lane = tid & 63;
  const int wv = tid >> 6;
  const int lc = lane & 15, lq = lane >> 4;
  const int b = blockIdx.x;
  alignas(16) unsigned short tmp[8];
  if (b < 1024) {
    const int r = b * 4 + wv;  // 0..4095 = (n,tt,kc)
    const int kc = r & 7, tt = (r >> 3) & 127, n = r >> 10;
    const int t = tt * 16 + lc;
    const int c0 = kc * 32 + lq * 8;
    const float* src = x + (size_t)(n * 256 + c0) * 2048 + t;
#pragma unroll
    for (int j = 0; j < 8; ++j) tmp[j] = f2bf(src[(size_t)j * 2048]);
    unsigned short* dst = ws + (WS_X >> 1) + (size_t)r * 512 + lane * 8;
    *(int4*)dst = *(const int4*)tmp;
  } else {
    const int r = (b - 1024) * 4 + wv;  // 0..383 = (wi,ot,kc)
    const int kc = r & 7, ot = (r >> 3) & 15, wi = r >> 7;
    const float* W = (wi == 0) ? Wq : (wi == 1) ? Wk : Wv;
    const float scale = (wi == 0) ? 0.25503492f : 1.0f;  // log2(e)/sqrt(32)
    const int o = ot * 16 + lc;
    const int c0 = kc * 32 + lq * 8;
    const float* src = W + o * 256 + c0;
#pragma unroll
    for (int j = 0; j < 8; ++j) tmp[j] = f2bf(src[j] * scale);
    unsigned short* dst = ws + (WS_W >> 1) + (size_t)r * 512 + lane * 8;
    *(int4*)dst = *(const int4*)tmp;
  }
}

// ---------------- projection GEMM: Q/K/V = W * x, frag-packed outputs ----------
__global__ __launch_bounds__(256) void proj_kernel(unsigned short* __restrict__ ws) {
  __shared__ unsigned short eps[4][2048];  // per-wave 4KB swizzle buffer (Q/K only)
  const int tid = threadIdx.x, lane = tid & 63, w = tid >> 6;
  const int lc = lane & 15, lq = lane >> 4;
  const int tt2 = blockIdx.x;  // 0..63 : t-range of 32
  const int n = blockIdx.y;    // 0..3
  const int wi = blockIdx.z;   // 0=Q 1=K 2=V
  const unsigned short* Xb = ws + (WS_X >> 1);
  const unsigned short* Wb = ws + (WS_W >> 1);

  short8 af[2][8];
#pragma unroll
  for (int mt = 0; mt < 2; ++mt)
#pragma unroll
    for (int kc = 0; kc < 8; ++kc)
      af[mt][kc] = *(const short8*)(Xb + ((size_t)((n * 128 + tt2 * 2 + mt) * 8 + kc) * 512 + lane * 8));

  f32x4 acc[2][4];
#pragma unroll
  for (int mt = 0; mt < 2; ++mt)
#pragma unroll
    for (int nt = 0; nt < 4; ++nt) {
      f32x4 z = {0.f, 0.f, 0.f, 0.f};
      acc[mt][nt] = z;
    }

#pragma unroll
  for (int kc = 0; kc < 8; ++kc) {
    short8 bf[4];
#pragma unroll
    for (int nt = 0; nt < 4; ++nt)
      bf[nt] = *(const short8*)(Wb + ((size_t)((wi * 16 + w * 4 + nt) * 8 + kc) * 512 + lane * 8));
#pragma unroll
    for (int mt = 0; mt < 2; ++mt)
#pragma unroll
      for (int nt = 0; nt < 4; ++nt)
        acc[mt][nt] = __builtin_amdgcn_mfma_f32_16x16x32_bf16(af[mt][kc], bf[nt], acc[mt][nt], 0, 0, 0);
  }

  // C layout: value (mt,nt,r) at lane(lc,lq) is element (t = tt2*32+mt*16+lq*4+r,
  //                                                      o = w*64+nt*16+lc)
  if (wi < 2) {
    unsigned short* ep = eps[w];
#pragma unroll
    for (int mt = 0; mt < 2; ++mt)
#pragma unroll
      for (int nt = 0; nt < 4; ++nt) {
        const int m2 = ((nt & 1) << 1) | (lc >> 3);
        const int base = ((mt * 2 + (nt >> 1)) << 9) + (m2 << 7) + (lq << 5) + (lc & 7);
#pragma unroll
        for (int r = 0; r < 4; ++r)
          ep[base + ((r ^ m2) << 3)] = f2bf(acc[mt][nt][r]);
      }
    const int swzl = lane ^ (lane >> 4);
    unsigned short* dst = ws + ((wi == 0) ? (WS_Q >> 1) : (WS_K >> 1));
#pragma unroll
    for (int rl = 0; rl < 4; ++rl) {
      int4 v = *(const int4*)(ep + (rl << 9) + swzl * 8);
      const int mt = rl >> 1, hh = rl & 1;
      const int nh = n * 8 + w * 2 + hh;
      const int ttg = tt2 * 2 + mt;
      *(int4*)(dst + ((size_t)(nh * 128 + ttg) * 64 + lane) * 8) = v;
    }
  } else {
    // V: target [nh][kb][dt][sbp][lane][half*4+j] -- lane mapping is IDENTITY.
    const int kb = tt2 >> 1, sbp = tt2 & 1;
#pragma unroll
    for (int nt = 0; nt < 4; ++nt) {
      const int nh = n * 8 + w * 2 + (nt >> 1);
      const int dt = nt & 1;
      alignas(16) unsigned short tmp[8];
#pragma unroll
      for (int mt = 0; mt < 2; ++mt)
#pragma unroll
        for (int r = 0; r < 4; ++r) tmp[mt * 4 + r] = f2bf(acc[mt][nt][r]);
      unsigned short* dstv = ws + (WS_V >> 1) +
          ((size_t)((((nh * 32 + kb) * 2 + dt) * 2 + sbp)) * 64 + lane) * 8;
      *(int4*)dstv = *(const int4*)tmp;
    }
  }
}

// ------ fused flash attention: KS=1, barrier-free, XCD-pinned chunks ----------
// blockIdx.x = qx*32 + nh; linear%8 = nh&7 pins each head's blocks to one XCD
// (K/V L2 locality). 1024 blocks x 2 waves = 2048 waves (2/SIMD). Each wave:
// 32 q rows (2 q-frags) x 32 kb-blocks of 64 keys. Per-sb streaming:
// {2 QK MFMA -> 8 exp2 -> 4 pack -> 2 lsum-MFMA (ones B) -> 4 PV MFMA}.
// K reloaded per-sb in place; V staggered in-place (prefetch distance 1; the
// last-iter overrun reads the next ws region, values never consumed).
// Epilogue: lsum_acc rows == acc rows -> per-lane normalize, direct f32 store.
__global__ __launch_bounds__(128, 2) void attn_kernel(
    const unsigned short* __restrict__ ws, float* __restrict__ out) {
  const int tid = threadIdx.x;
  const int lane = tid & 63, wv = tid >> 6;
  const int lc = lane & 15, quad = lane >> 4;
  const int c = blockIdx.x & 31;
  const int qx = blockIdx.x >> 5;   // 0..31
  const int nh = c;                 // chunk -> XCD pin: nh&7
  const int qw = qx * 2 + wv;       // 0..63 -> q rows qw*32 .. +31

  const unsigned short* Qw = ws + (WS_Q >> 1) + ((size_t)(nh * 128 + qw * 2)) * 512;
  const unsigned short* Kb = ws + (WS_K >> 1) + (size_t)nh * 65536;
  const unsigned short* Vb = ws + (WS_V >> 1) + (size_t)nh * 65536;

  // Q B-frags (16x16x32): n=query on lane&15, k=dk on quad*8+j. Loaded once.
  short8 qf[2];
  qf[0] = *(const short8*)(Qw + lane * 8);
  qf[1] = *(const short8*)(Qw + 512 + lane * 8);

  f32x4 acc[2][2];
  f32x4 lsum_acc[2];
#pragma unroll
  for (int mt = 0; mt < 2; ++mt) {
    f32x4 z = {0.f, 0.f, 0.f, 0.f};
    acc[mt][0] = z;
    acc[mt][1] = z;
    lsum_acc[mt] = z;
  }
  // B-frag of all-ones bf16: D = P * ones -> every column = rowsum(P).
  const short4v onesf = {(short)0x3F80, (short)0x3F80, (short)0x3F80, (short)0x3F80};

  short8 kf[4], vv[4];
  {
    const unsigned short* kp = Kb + lane * 8;
    const unsigned short* vp = Vb + lane * 8;
#pragma unroll
    for (int u = 0; u < 4; ++u) kf[u] = *(const short8*)(kp + u * 512);
#pragma unroll
    for (int u = 0; u < 4; ++u) vv[u] = *(const short8*)(vp + u * 512);
  }

#pragma unroll 2
  for (int kb = 0; kb < 32; ++kb) {
    // prefetch pointers for next kb (last iter reads 1 block past the chunk:
    // stays inside initialized ws regions, values never consumed)
    const unsigned short* nkp = Kb + (size_t)(kb + 1) * 2048 + lane * 8;
    const unsigned short* nvp = Vb + (size_t)(kb + 1) * 2048 + lane * 8;
#pragma unroll
    for (int sb = 0; sb < 4; ++sb) {
      // V B-frags for this 16-key slice: sbp = sb>>1, half = sb&1
      const short8 t0 = vv[(sb >> 1)];      // dt=0
      const short8 t1 = vv[2 + (sb >> 1)];  // dt=1
      short4v vf0, vf1;
      if (sb & 1) {
        vf0 = __builtin_shufflevector(t0, t0, 4, 5, 6, 7);
        vf1 = __builtin_shufflevector(t1, t1, 4, 5, 6, 7);
      } else {
        vf0 = __builtin_shufflevector(t0, t0, 0, 1, 2, 3);
        vf1 = __builtin_shufflevector(t1, t1, 0, 1, 2, 3);
      }
      // S^T = K * Q^T (A=K m=key, B=Q n=query); C-layout == A-frag of 16x16x16
      f32x4 st[2];
#pragma unroll
      for (int mt = 0; mt < 2; ++mt) {
        f32x4 z = {0.f, 0.f, 0.f, 0.f};
        st[mt] = __builtin_amdgcn_mfma_f32_16x16x32_bf16(kf[sb], qf[mt], z, 0, 0, 0);
      }
      // kf[sb] dead now -> reload for next kb (3/4-kb prefetch distance)
      kf[sb] = *(const short8*)(nkp + sb * 512);
      // staggered in-place V reload: vv[0],vv[2] dead after sb=1; vv[1],vv[3] after sb=3
      if (sb == 1) {
        vv[0] = *(const short8*)(nvp + 0 * 512);
        vv[2] = *(const short8*)(nvp + 2 * 512);
      }
      if (sb == 3) {
        vv[1] = *(const short8*)(nvp + 1 * 512);
        vv[3] = *(const short8*)(nvp + 3 * 512);
      }
#pragma unroll
      for (int mt = 0; mt < 2; ++mt) {
        const float p0 = __builtin_amdgcn_exp2f(st[mt][0]);
        const float p1 = __builtin_amdgcn_exp2f(st[mt][1]);
        const float p2 = __builtin_amdgcn_exp2f(st[mt][2]);
        const float p3 = __builtin_amdgcn_exp2f(st[mt][3]);
        int2 pi;
        pi.x = pack_bf16rn(p0, p1);
        pi.y = pack_bf16rn(p2, p3);
        const short4v pf = __builtin_bit_cast(short4v, pi);
        // rowsum on the MFMA pipe; denominator == sum of the bf16 p's used in PV
        lsum_acc[mt] = __builtin_amdgcn_mfma_f32_16x16x16bf16_1k(pf, onesf, lsum_acc[mt], 0, 0, 0);
        acc[mt][0] = __builtin_amdgcn_mfma_f32_16x16x16bf16_1k(pf, vf0, acc[mt][0], 0, 0, 0);
        acc[mt][1] = __builtin_amdgcn_mfma_f32_16x16x16bf16_1k(pf, vf1, acc[mt][1], 0, 0, 0);
      }
    }
  }

  // Normalize + direct store. acc C-layout: col=lc=d, row=quad*4+r=q (+mt*16);
  // lsum_acc rows identical -> per-lane elementwise, no shuffles.
  const int chbase = (nh >> 3) * 256 + (nh & 7) * 32;
#pragma unroll
  for (int mt = 0; mt < 2; ++mt) {
    f32x4 is;
#pragma unroll
    for (int r = 0; r < 4; ++r) is[r] = 1.0f / lsum_acc[mt][r];
    const int tb = qw * 32 + mt * 16 + quad * 4;
#pragma unroll
    for (int dt = 0; dt < 2; ++dt) {
      f32x4 ov;
#pragma unroll
      for (int r = 0; r < 4; ++r) ov[r] = acc[mt][dt][r] * is[r];
      *(f32x4*)(out + (size_t)(chbase + dt * 16 + lc) * 2048 + tb) = ov;
    }
  }
}

extern "C" void kernel_launch(void* const* d_in, const int* in_sizes, int n_in,
                              void* d_out, int out_size, void* d_ws, size_t ws_size,
                              hipStream_t stream) {
  const float* x = (const float*)d_in[0];
  const float* Wq = (const float*)d_in[1];
  const float* Wk = (const float*)d_in[2];
  const float* Wv = (const float*)d_in[3];
  unsigned short* ws = (unsigned short*)d_ws;
  float* out = (float*)d_out;
  (void)in_sizes; (void)n_in; (void)out_size; (void)ws_size;

  pack_kernel<<<1120, 256, 0, stream>>>(x, Wq, Wk, Wv, ws);
  proj_kernel<<<dim3(64, 4, 3), 256, 0, stream>>>(ws);
  attn_kernel<<<1024, 128, 0, stream>>>(ws, out);
}

// Round 8
// 110.044 us; speedup vs baseline: 1.4642x; 1.0181x over previous
//
#include <hip/hip_runtime.h>

// MultiHeadAttn1D: N=4, C=256, T=2048, H=8, dk=dv=32.
// ws layout (bytes):
//   [0   , 4Mi ) Q_ws  bf16 B-frag (16x16x32): [nh(32)][qtile(128)][lane(64)][8]
//                lane=(t&15)+16*(d>>3), j=d&7   (Q pre-scaled by log2e/sqrt(32))
//   [4Mi , 8Mi ) K_ws  bf16 A-frag (16x16x32): [nh][ktile(128)][lane][8]
//   [8Mi ,12Mi ) V_ws  bf16 B-frag (16x16x16): [nh][kb(32)][dt(2)][sbp(2)][lane][8]
//   [12Mi,16Mi ) Xb    bf16 A-frag x: [n(4)][tt(128)][kc(8)][lane][8]
//   [16Mi,16.4Mi) Wb   bf16 B-frag W: [wi(3)][ot(16)][kc(8)][lane][8]
//
// R12 (this round): attn softmax pack 3 instr -> 1 instr (truncating
// v_perm_b32). Rationale: five structurally different attn configs (2-8
// waves/SIMD, 128-512MB load volume, batched vs streamed softmax) all give
// T_attn ~= 25.7us; every throughput ceiling (MFMA 2.1, trans 3.4, packs 2.6,
// TA ~7-14, L2 7-15us) is far below 25.7 and TLP-invariance kills latency/BW
// theories -> attn is instruction-ISSUE-bound; softmax = 224 of ~280 issue
// cyc/kb (exp 128 + pack 96). Truncation is numerically safe here: lsum is
// accumulated (via ones-MFMA) from the SAME truncated bf16 P values, so the
// uniform -2^-9 bias cancels exactly in P/sum(P); only +-2^-9 reweighting
// noise survives (absmax ~6-10e-4 vs 1.99e-3 threshold).
// Everything else identical to R11 (passing): KS=1, 3 dispatches, per-sb
// streaming, lsum via ones-MFMA, staggered in-place K/V reloads.

typedef float f32x4 __attribute__((ext_vector_type(4)));
typedef short short8 __attribute__((ext_vector_type(8)));
typedef short short4v __attribute__((ext_vector_type(4)));

#define WS_Q 0u
#define WS_K (4u << 20)
#define WS_V (8u << 20)
#define WS_X (12u << 20)
#define WS_W (16u << 20)

__device__ __forceinline__ unsigned short f2bf(float f) {
  unsigned int u = __builtin_bit_cast(unsigned int, f);
  u += 0x7FFFu + ((u >> 16) & 1u);
  return (unsigned short)(u >> 16);
}

// pack two floats to bf16 (RNE) into one dword: [bf(a) | bf(b)<<16]
__device__ __forceinline__ int pack_bf16rn(float a, float b) {
  unsigned int ua = __builtin_bit_cast(unsigned int, a) + 0x8000u;
  unsigned int ub = __builtin_bit_cast(unsigned int, b) + 0x8000u;
  return __builtin_amdgcn_perm(ub, ua, 0x07060302);
}

// TRUNCATING pack: single v_perm_b32. Systematic -2^-9 bias cancels in
// softmax normalization (lsum built from the same truncated values).
__device__ __forceinline__ int pack_bf16tr(float a, float b) {
  return __builtin_amdgcn_perm(__builtin_bit_cast(unsigned int, b),
                               __builtin_bit_cast(unsigned int, a), 0x07060302);
}

// ---------------- pack: x -> Xb (bf16 A-frags), W -> Wb (bf16 B-frags) ---------
__global__ __launch_bounds__(256) void pack_kernel(
    const float* __restrict__ x, const float* __restrict__ Wq,
    const float* __restrict__ Wk, const float* __restrict__ Wv,
    unsigned short* __restrict__ ws) {
  const int tid = threadIdx.x;
  const int lane = tid & 63;
  const int wv = tid >> 6;
  const int lc = lane & 15, lq = lane >> 4;
  const int b = blockIdx.x;
  alignas(16) unsigned short tmp[8];
  if (b < 1024) {
    const int r = b * 4 + wv;  // 0..4095 = (n,tt,kc)
    const int kc = r & 7, tt = (r >> 3) & 127, n = r >> 10;
    const int t = tt * 16 + lc;
    const int c0 = kc * 32 + lq * 8;
    const float* src = x + (size_t)(n * 256 + c0) * 2048 + t;
#pragma unroll
    for (int j = 0; j < 8; ++j) tmp[j] = f2bf(src[(size_t)j * 2048]);
    unsigned short* dst = ws + (WS_X >> 1) + (size_t)r * 512 + lane * 8;
    *(int4*)dst = *(const int4*)tmp;
  } else {
    const int r = (b - 1024) * 4 + wv;  // 0..383 = (wi,ot,kc)
    const int kc = r & 7, ot = (r >> 3) & 15, wi = r >> 7;
    const float* W = (wi == 0) ? Wq : (wi == 1) ? Wk : Wv;
    const float scale = (wi == 0) ? 0.25503492f : 1.0f;  // log2(e)/sqrt(32)
    const int o = ot * 16 + lc;
    const int c0 = kc * 32 + lq * 8;
    const float* src = W + o * 256 + c0;
#pragma unroll
    for (int j = 0; j < 8; ++j) tmp[j] = f2bf(src[j] * scale);
    unsigned short* dst = ws + (WS_W >> 1) + (size_t)r * 512 + lane * 8;
    *(int4*)dst = *(const int4*)tmp;
  }
}

// ---------------- projection GEMM: Q/K/V = W * x, frag-packed outputs ----------
__global__ __launch_bounds__(256) void proj_kernel(unsigned short* __restrict__ ws) {
  __shared__ unsigned short eps[4][2048];  // per-wave 4KB swizzle buffer (Q/K only)
  const int tid = threadIdx.x, lane = tid & 63, w = tid >> 6;
  const int lc = lane & 15, lq = lane >> 4;
  const int tt2 = blockIdx.x;  // 0..63 : t-range of 32
  const int n = blockIdx.y;    // 0..3
  const int wi = blockIdx.z;   // 0=Q 1=K 2=V
  const unsigned short* Xb = ws + (WS_X >> 1);
  const unsigned short* Wb = ws + (WS_W >> 1);

  short8 af[2][8];
#pragma unroll
  for (int mt = 0; mt < 2; ++mt)
#pragma unroll
    for (int kc = 0; kc < 8; ++kc)
      af[mt][kc] = *(const short8*)(Xb + ((size_t)((n * 128 + tt2 * 2 + mt) * 8 + kc) * 512 + lane * 8));

  f32x4 acc[2][4];
#pragma unroll
  for (int mt = 0; mt < 2; ++mt)
#pragma unroll
    for (int nt = 0; nt < 4; ++nt) {
      f32x4 z = {0.f, 0.f, 0.f, 0.f};
      acc[mt][nt] = z;
    }

#pragma unroll
  for (int kc = 0; kc < 8; ++kc) {
    short8 bf[4];
#pragma unroll
    for (int nt = 0; nt < 4; ++nt)
      bf[nt] = *(const short8*)(Wb + ((size_t)((wi * 16 + w * 4 + nt) * 8 + kc) * 512 + lane * 8));
#pragma unroll
    for (int mt = 0; mt < 2; ++mt)
#pragma unroll
      for (int nt = 0; nt < 4; ++nt)
        acc[mt][nt] = __builtin_amdgcn_mfma_f32_16x16x32_bf16(af[mt][kc], bf[nt], acc[mt][nt], 0, 0, 0);
  }

  // C layout: value (mt,nt,r) at lane(lc,lq) is element (t = tt2*32+mt*16+lq*4+r,
  //                                                      o = w*64+nt*16+lc)
  if (wi < 2) {
    unsigned short* ep = eps[w];
#pragma unroll
    for (int mt = 0; mt < 2; ++mt)
#pragma unroll
      for (int nt = 0; nt < 4; ++nt) {
        const int m2 = ((nt & 1) << 1) | (lc >> 3);
        const int base = ((mt * 2 + (nt >> 1)) << 9) + (m2 << 7) + (lq << 5) + (lc & 7);
#pragma unroll
        for (int r = 0; r < 4; ++r)
          ep[base + ((r ^ m2) << 3)] = f2bf(acc[mt][nt][r]);
      }
    const int swzl = lane ^ (lane >> 4);
    unsigned short* dst = ws + ((wi == 0) ? (WS_Q >> 1) : (WS_K >> 1));
#pragma unroll
    for (int rl = 0; rl < 4; ++rl) {
      int4 v = *(const int4*)(ep + (rl << 9) + swzl * 8);
      const int mt = rl >> 1, hh = rl & 1;
      const int nh = n * 8 + w * 2 + hh;
      const int ttg = tt2 * 2 + mt;
      *(int4*)(dst + ((size_t)(nh * 128 + ttg) * 64 + lane) * 8) = v;
    }
  } else {
    // V: target [nh][kb][dt][sbp][lane][half*4+j] -- lane mapping is IDENTITY.
    const int kb = tt2 >> 1, sbp = tt2 & 1;
#pragma unroll
    for (int nt = 0; nt < 4; ++nt) {
      const int nh = n * 8 + w * 2 + (nt >> 1);
      const int dt = nt & 1;
      alignas(16) unsigned short tmp[8];
#pragma unroll
      for (int mt = 0; mt < 2; ++mt)
#pragma unroll
        for (int r = 0; r < 4; ++r) tmp[mt * 4 + r] = f2bf(acc[mt][nt][r]);
      unsigned short* dstv = ws + (WS_V >> 1) +
          ((size_t)((((nh * 32 + kb) * 2 + dt) * 2 + sbp)) * 64 + lane) * 8;
      *(int4*)dstv = *(const int4*)tmp;
    }
  }
}

// ------ fused flash attention: KS=1, barrier-free, XCD-pinned chunks ----------
// blockIdx.x = qx*32 + nh; linear%8 = nh&7 pins each head's blocks to one XCD
// (K/V L2 locality). 1024 blocks x 2 waves = 2048 waves (2/SIMD). Each wave:
// 32 q rows (2 q-frags) x 32 kb-blocks of 64 keys. Per-sb streaming:
// {2 QK MFMA -> 8 exp2 -> 2 perm-pack -> 2 lsum-MFMA (ones B) -> 4 PV MFMA}.
// K reloaded per-sb in place; V staggered in-place (prefetch distance 1; the
// last-iter overrun reads the next ws region, values never consumed).
// Epilogue: lsum_acc rows == acc rows -> per-lane normalize, direct f32 store.
__global__ __launch_bounds__(128, 2) void attn_kernel(
    const unsigned short* __restrict__ ws, float* __restrict__ out) {
  const int tid = threadIdx.x;
  const int lane = tid & 63, wv = tid >> 6;
  const int lc = lane & 15, quad = lane >> 4;
  const int c = blockIdx.x & 31;
  const int qx = blockIdx.x >> 5;   // 0..31
  const int nh = c;                 // chunk -> XCD pin: nh&7
  const int qw = qx * 2 + wv;       // 0..63 -> q rows qw*32 .. +31

  const unsigned short* Qw = ws + (WS_Q >> 1) + ((size_t)(nh * 128 + qw * 2)) * 512;
  const unsigned short* Kb = ws + (WS_K >> 1) + (size_t)nh * 65536;
  const unsigned short* Vb = ws + (WS_V >> 1) + (size_t)nh * 65536;

  // Q B-frags (16x16x32): n=query on lane&15, k=dk on quad*8+j. Loaded once.
  short8 qf[2];
  qf[0] = *(const short8*)(Qw + lane * 8);
  qf[1] = *(const short8*)(Qw + 512 + lane * 8);

  f32x4 acc[2][2];
  f32x4 lsum_acc[2];
#pragma unroll
  for (int mt = 0; mt < 2; ++mt) {
    f32x4 z = {0.f, 0.f, 0.f, 0.f};
    acc[mt][0] = z;
    acc[mt][1] = z;
    lsum_acc[mt] = z;
  }
  // B-frag of all-ones bf16: D = P * ones -> every column = rowsum(P).
  const short4v onesf = {(short)0x3F80, (short)0x3F80, (short)0x3F80, (short)0x3F80};

  short8 kf[4], vv[4];
  {
    const unsigned short* kp = Kb + lane * 8;
    const unsigned short* vp = Vb + lane * 8;
#pragma unroll
    for (int u = 0; u < 4; ++u) kf[u] = *(const short8*)(kp + u * 512);
#pragma unroll
    for (int u = 0; u < 4; ++u) vv[u] = *(const short8*)(vp + u * 512);
  }

#pragma unroll 4
  for (int kb = 0; kb < 32; ++kb) {
    // prefetch pointers for next kb (last iter reads 1 block past the chunk:
    // stays inside initialized ws regions, values never consumed)
    const unsigned short* nkp = Kb + (size_t)(kb + 1) * 2048 + lane * 8;
    const unsigned short* nvp = Vb + (size_t)(kb + 1) * 2048 + lane * 8;
#pragma unroll
    for (int sb = 0; sb < 4; ++sb) {
      // V B-frags for this 16-key slice: sbp = sb>>1, half = sb&1
      // (shufflevector of reg halves = register aliasing, no instructions)
      const short8 t0 = vv[(sb >> 1)];      // dt=0
      const short8 t1 = vv[2 + (sb >> 1)];  // dt=1
      short4v vf0, vf1;
      if (sb & 1) {
        vf0 = __builtin_shufflevector(t0, t0, 4, 5, 6, 7);
        vf1 = __builtin_shufflevector(t1, t1, 4, 5, 6, 7);
      } else {
        vf0 = __builtin_shufflevector(t0, t0, 0, 1, 2, 3);
        vf1 = __builtin_shufflevector(t1, t1, 0, 1, 2, 3);
      }
      // S^T = K * Q^T (A=K m=key, B=Q n=query); C-layout == A-frag of 16x16x16
      f32x4 st[2];
#pragma unroll
      for (int mt = 0; mt < 2; ++mt) {
        f32x4 z = {0.f, 0.f, 0.f, 0.f};
        st[mt] = __builtin_amdgcn_mfma_f32_16x16x32_bf16(kf[sb], qf[mt], z, 0, 0, 0);
      }
      // kf[sb] dead now -> reload for next kb (3/4-kb prefetch distance)
      kf[sb] = *(const short8*)(nkp + sb * 512);
      // staggered in-place V reload: vv[0],vv[2] dead after sb=1; vv[1],vv[3] after sb=3
      if (sb == 1) {
        vv[0] = *(const short8*)(nvp + 0 * 512);
        vv[2] = *(const short8*)(nvp + 2 * 512);
      }
      if (sb == 3) {
        vv[1] = *(const short8*)(nvp + 1 * 512);
        vv[3] = *(const short8*)(nvp + 3 * 512);
      }
#pragma unroll
      for (int mt = 0; mt < 2; ++mt) {
        const float p0 = __builtin_amdgcn_exp2f(st[mt][0]);
        const float p1 = __builtin_amdgcn_exp2f(st[mt][1]);
        const float p2 = __builtin_amdgcn_exp2f(st[mt][2]);
        const float p3 = __builtin_amdgcn_exp2f(st[mt][3]);
        int2 pi;
        pi.x = pack_bf16tr(p0, p1);  // 1 instr/pair (was 3)
        pi.y = pack_bf16tr(p2, p3);
        const short4v pf = __builtin_bit_cast(short4v, pi);
        // rowsum on the MFMA pipe; denominator == sum of the SAME truncated
        // bf16 p's used in PV -> truncation bias cancels in P/sum(P).
        lsum_acc[mt] = __builtin_amdgcn_mfma_f32_16x16x16bf16_1k(pf, onesf, lsum_acc[mt], 0, 0, 0);
        acc[mt][0] = __builtin_amdgcn_mfma_f32_16x16x16bf16_1k(pf, vf0, acc[mt][0], 0, 0, 0);
        acc[mt][1] = __builtin_amdgcn_mfma_f32_16x16x16bf16_1k(pf, vf1, acc[mt][1], 0, 0, 0);
      }
    }
  }

  // Normalize + direct store. acc C-layout: col=lc=d, row=quad*4+r=q (+mt*16);
  // lsum_acc rows identical -> per-lane elementwise, no shuffles.
  const int chbase = (nh >> 3) * 256 + (nh & 7) * 32;
#pragma unroll
  for (int mt = 0; mt < 2; ++mt) {
    f32x4 is;
#pragma unroll
    for (int r = 0; r < 4; ++r) is[r] = 1.0f / lsum_acc[mt][r];
    const int tb = qw * 32 + mt * 16 + quad * 4;
#pragma unroll
    for (int dt = 0; dt < 2; ++dt) {
      f32x4 ov;
#pragma unroll
      for (int r = 0; r < 4; ++r) ov[r] = acc[mt][dt][r] * is[r];
      *(f32x4*)(out + (size_t)(chbase + dt * 16 + lc) * 2048 + tb) = ov;
    }
  }
}

extern "C" void kernel_launch(void* const* d_in, const int* in_sizes, int n_in,
                              void* d_out, int out_size, void* d_ws, size_t ws_size,
                              hipStream_t stream) {
  const float* x = (const float*)d_in[0];
  const float* Wq = (const float*)d_in[1];
  const float* Wk = (const float*)d_in[2];
  const float* Wv = (const float*)d_in[3];
  unsigned short* ws = (unsigned short*)d_ws;
  float* out = (float*)d_out;
  (void)in_sizes; (void)n_in; (void)out_size; (void)ws_size;

  pack_kernel<<<1120, 256, 0, stream>>>(x, Wq, Wk, Wv, ws);
  proj_kernel<<<dim3(64, 4, 3), 256, 0, stream>>>(ws);
  attn_kernel<<<1024, 128, 0, stream>>>(ws, out);
}

// Round 9
// 109.284 us; speedup vs baseline: 1.4744x; 1.0070x over previous
//
#include <hip/hip_runtime.h>

// MultiHeadAttn1D: N=4, C=256, T=2048, H=8, dk=dv=32.
// ws layout (bytes):
//   [0   , 4Mi ) Q_ws  bf16 B-frag (16x16x32): [nh(32)][qtile(128)][lane(64)][8]
//                lane=(t&15)+16*(d>>3), j=d&7   (Q pre-scaled by log2e/sqrt(32))
//   [4Mi , 8Mi ) K_ws  bf16 A-frag (16x16x32): [nh][ktile(128)][lane][8]
//   [8Mi ,12Mi ) V_ws  bf16 B-frag (16x16x16): [nh][kb(32)][dt(2)][sbp(2)][lane][8]
//   [12Mi,16Mi ) Xb    bf16 A-frag x: [n(4)][tt(128)][kc(8)][lane][8]
//   [16Mi,16.4Mi) Wb   bf16 B-frag W: [wi(3)][ot(16)][kc(8)][lane][8]
//
// R13 (this round): ILP-2 in attn. Ledger: TLP (2-5 waves/SIMD), load volume
// (2x), VALU (-25%), spills, dispatches -- all eliminated; attn stuck ~25.7us
// vs ~8-15us throughput models. Last untested mechanism: each wave runs ONE
// serial QK->exp->pack->PV chain; per-sb critical path ~2x issue work; both
// resident waves stall at the same points. Fix: process TWO kb-blocks per
// wave concurrently (even/odd, stride 2) with independent kf/vv/st/pf and
// SHARED acc/lsum (MFMA accumulation order-insensitive). Chain B's exp/loads
// fill chain A's MFMA-latency shadows. ~150 VGPR live under (128,2)'s 256
// cap. Everything else identical to passing R12 (KS=1, 3 dispatches,
// truncating pack, lsum via ones-MFMA, staggered in-place K/V reloads).

typedef float f32x4 __attribute__((ext_vector_type(4)));
typedef short short8 __attribute__((ext_vector_type(8)));
typedef short short4v __attribute__((ext_vector_type(4)));

#define WS_Q 0u
#define WS_K (4u << 20)
#define WS_V (8u << 20)
#define WS_X (12u << 20)
#define WS_W (16u << 20)

__device__ __forceinline__ unsigned short f2bf(float f) {
  unsigned int u = __builtin_bit_cast(unsigned int, f);
  u += 0x7FFFu + ((u >> 16) & 1u);
  return (unsigned short)(u >> 16);
}

// pack two floats to bf16 (RNE) into one dword: [bf(a) | bf(b)<<16]
__device__ __forceinline__ int pack_bf16rn(float a, float b) {
  unsigned int ua = __builtin_bit_cast(unsigned int, a) + 0x8000u;
  unsigned int ub = __builtin_bit_cast(unsigned int, b) + 0x8000u;
  return __builtin_amdgcn_perm(ub, ua, 0x07060302);
}

// TRUNCATING pack: single v_perm_b32. Systematic -2^-9 bias cancels in
// softmax normalization (lsum built from the same truncated values).
__device__ __forceinline__ int pack_bf16tr(float a, float b) {
  return __builtin_amdgcn_perm(__builtin_bit_cast(unsigned int, b),
                               __builtin_bit_cast(unsigned int, a), 0x07060302);
}

// ---------------- pack: x -> Xb (bf16 A-frags), W -> Wb (bf16 B-frags) ---------
__global__ __launch_bounds__(256) void pack_kernel(
    const float* __restrict__ x, const float* __restrict__ Wq,
    const float* __restrict__ Wk, const float* __restrict__ Wv,
    unsigned short* __restrict__ ws) {
  const int tid = threadIdx.x;
  const int lane = tid & 63;
  const int wv = tid >> 6;
  const int lc = lane & 15, lq = lane >> 4;
  const int b = blockIdx.x;
  alignas(16) unsigned short tmp[8];
  if (b < 1024) {
    const int r = b * 4 + wv;  // 0..4095 = (n,tt,kc)
    const int kc = r & 7, tt = (r >> 3) & 127, n = r >> 10;
    const int t = tt * 16 + lc;
    const int c0 = kc * 32 + lq * 8;
    const float* src = x + (size_t)(n * 256 + c0) * 2048 + t;
#pragma unroll
    for (int j = 0; j < 8; ++j) tmp[j] = f2bf(src[(size_t)j * 2048]);
    unsigned short* dst = ws + (WS_X >> 1) + (size_t)r * 512 + lane * 8;
    *(int4*)dst = *(const int4*)tmp;
  } else {
    const int r = (b - 1024) * 4 + wv;  // 0..383 = (wi,ot,kc)
    const int kc = r & 7, ot = (r >> 3) & 15, wi = r >> 7;
    const float* W = (wi == 0) ? Wq : (wi == 1) ? Wk : Wv;
    const float scale = (wi == 0) ? 0.25503492f : 1.0f;  // log2(e)/sqrt(32)
    const int o = ot * 16 + lc;
    const int c0 = kc * 32 + lq * 8;
    const float* src = W + o * 256 + c0;
#pragma unroll
    for (int j = 0; j < 8; ++j) tmp[j] = f2bf(src[j] * scale);
    unsigned short* dst = ws + (WS_W >> 1) + (size_t)r * 512 + lane * 8;
    *(int4*)dst = *(const int4*)tmp;
  }
}

// ---------------- projection GEMM: Q/K/V = W * x, frag-packed outputs ----------
__global__ __launch_bounds__(256) void proj_kernel(unsigned short* __restrict__ ws) {
  __shared__ unsigned short eps[4][2048];  // per-wave 4KB swizzle buffer (Q/K only)
  const int tid = threadIdx.x, lane = tid & 63, w = tid >> 6;
  const int lc = lane & 15, lq = lane >> 4;
  const int tt2 = blockIdx.x;  // 0..63 : t-range of 32
  const int n = blockIdx.y;    // 0..3
  const int wi = blockIdx.z;   // 0=Q 1=K 2=V
  const unsigned short* Xb = ws + (WS_X >> 1);
  const unsigned short* Wb = ws + (WS_W >> 1);

  short8 af[2][8];
#pragma unroll
  for (int mt = 0; mt < 2; ++mt)
#pragma unroll
    for (int kc = 0; kc < 8; ++kc)
      af[mt][kc] = *(const short8*)(Xb + ((size_t)((n * 128 + tt2 * 2 + mt) * 8 + kc) * 512 + lane * 8));

  f32x4 acc[2][4];
#pragma unroll
  for (int mt = 0; mt < 2; ++mt)
#pragma unroll
    for (int nt = 0; nt < 4; ++nt) {
      f32x4 z = {0.f, 0.f, 0.f, 0.f};
      acc[mt][nt] = z;
    }

#pragma unroll
  for (int kc = 0; kc < 8; ++kc) {
    short8 bf[4];
#pragma unroll
    for (int nt = 0; nt < 4; ++nt)
      bf[nt] = *(const short8*)(Wb + ((size_t)((wi * 16 + w * 4 + nt) * 8 + kc) * 512 + lane * 8));
#pragma unroll
    for (int mt = 0; mt < 2; ++mt)
#pragma unroll
      for (int nt = 0; nt < 4; ++nt)
        acc[mt][nt] = __builtin_amdgcn_mfma_f32_16x16x32_bf16(af[mt][kc], bf[nt], acc[mt][nt], 0, 0, 0);
  }

  // C layout: value (mt,nt,r) at lane(lc,lq) is element (t = tt2*32+mt*16+lq*4+r,
  //                                                      o = w*64+nt*16+lc)
  if (wi < 2) {
    unsigned short* ep = eps[w];
#pragma unroll
    for (int mt = 0; mt < 2; ++mt)
#pragma unroll
      for (int nt = 0; nt < 4; ++nt) {
        const int m2 = ((nt & 1) << 1) | (lc >> 3);
        const int base = ((mt * 2 + (nt >> 1)) << 9) + (m2 << 7) + (lq << 5) + (lc & 7);
#pragma unroll
        for (int r = 0; r < 4; ++r)
          ep[base + ((r ^ m2) << 3)] = f2bf(acc[mt][nt][r]);
      }
    const int swzl = lane ^ (lane >> 4);
    unsigned short* dst = ws + ((wi == 0) ? (WS_Q >> 1) : (WS_K >> 1));
#pragma unroll
    for (int rl = 0; rl < 4; ++rl) {
      int4 v = *(const int4*)(ep + (rl << 9) + swzl * 8);
      const int mt = rl >> 1, hh = rl & 1;
      const int nh = n * 8 + w * 2 + hh;
      const int ttg = tt2 * 2 + mt;
      *(int4*)(dst + ((size_t)(nh * 128 + ttg) * 64 + lane) * 8) = v;
    }
  } else {
    // V: target [nh][kb][dt][sbp][lane][half*4+j] -- lane mapping is IDENTITY.
    const int kb = tt2 >> 1, sbp = tt2 & 1;
#pragma unroll
    for (int nt = 0; nt < 4; ++nt) {
      const int nh = n * 8 + w * 2 + (nt >> 1);
      const int dt = nt & 1;
      alignas(16) unsigned short tmp[8];
#pragma unroll
      for (int mt = 0; mt < 2; ++mt)
#pragma unroll
        for (int r = 0; r < 4; ++r) tmp[mt * 4 + r] = f2bf(acc[mt][nt][r]);
      unsigned short* dstv = ws + (WS_V >> 1) +
          ((size_t)((((nh * 32 + kb) * 2 + dt) * 2 + sbp)) * 64 + lane) * 8;
      *(int4*)dstv = *(const int4*)tmp;
    }
  }
}

// ------ fused flash attention: KS=1, barrier-free, XCD-pinned, ILP-2 ----------
// blockIdx.x = qx*32 + nh; linear%8 = nh&7 pins each head's blocks to one XCD.
// 1024 blocks x 2 waves = 2048 waves (2/SIMD). Each wave: 32 q rows x 32
// kb-blocks, processed as TWO concurrent chains (even kb / odd kb) with
// independent kf/vv/st/pf and shared acc/lsum. Per-sb per-chain:
// {2 QK MFMA -> 8 exp2 -> 2 perm-pack -> 1 lsum-MFMA (ones B) -> 2 PV MFMA}.
// K reloaded per-sb in place (+2 kb distance); V staggered in-place.
// Prefetch overruns (<=3 blocks past chunk) stay inside initialized ws.
__global__ __launch_bounds__(128, 2) void attn_kernel(
    const unsigned short* __restrict__ ws, float* __restrict__ out) {
  const int tid = threadIdx.x;
  const int lane = tid & 63, wv = tid >> 6;
  const int lc = lane & 15, quad = lane >> 4;
  const int c = blockIdx.x & 31;
  const int qx = blockIdx.x >> 5;   // 0..31
  const int nh = c;                 // chunk -> XCD pin: nh&7
  const int qw = qx * 2 + wv;       // 0..63 -> q rows qw*32 .. +31

  const unsigned short* Qw = ws + (WS_Q >> 1) + ((size_t)(nh * 128 + qw * 2)) * 512;
  const unsigned short* Kb = ws + (WS_K >> 1) + (size_t)nh * 65536;
  const unsigned short* Vb = ws + (WS_V >> 1) + (size_t)nh * 65536;

  // Q B-frags (16x16x32): n=query on lane&15, k=dk on quad*8+j. Loaded once.
  short8 qf[2];
  qf[0] = *(const short8*)(Qw + lane * 8);
  qf[1] = *(const short8*)(Qw + 512 + lane * 8);

  f32x4 acc[2][2];
  f32x4 lsum_acc[2];
#pragma unroll
  for (int mt = 0; mt < 2; ++mt) {
    f32x4 z = {0.f, 0.f, 0.f, 0.f};
    acc[mt][0] = z;
    acc[mt][1] = z;
    lsum_acc[mt] = z;
  }
  // B-frag of all-ones bf16: D = P * ones -> every column = rowsum(P).
  const short4v onesf = {(short)0x3F80, (short)0x3F80, (short)0x3F80, (short)0x3F80};

  // Two independent chains: A = even kb, B = odd kb.
  short8 kfA[4], vvA[4], kfB[4], vvB[4];
  {
    const unsigned short* kpA = Kb + lane * 8;
    const unsigned short* vpA = Vb + lane * 8;
    const unsigned short* kpB = Kb + 2048 + lane * 8;
    const unsigned short* vpB = Vb + 2048 + lane * 8;
#pragma unroll
    for (int u = 0; u < 4; ++u) kfA[u] = *(const short8*)(kpA + u * 512);
#pragma unroll
    for (int u = 0; u < 4; ++u) vvA[u] = *(const short8*)(vpA + u * 512);
#pragma unroll
    for (int u = 0; u < 4; ++u) kfB[u] = *(const short8*)(kpB + u * 512);
#pragma unroll
    for (int u = 0; u < 4; ++u) vvB[u] = *(const short8*)(vpB + u * 512);
  }

#pragma unroll 2
  for (int kb2 = 0; kb2 < 16; ++kb2) {
    // next-kb pointers for each chain (A: 2*kb2+2, B: 2*kb2+3). Final-iter
    // overruns read <=2 blocks past this head's K/V region: next head's
    // region (or V/X region for nh=31) -- initialized, values unused.
    const unsigned short* nkpA = Kb + (size_t)(2 * kb2 + 2) * 2048 + lane * 8;
    const unsigned short* nvpA = Vb + (size_t)(2 * kb2 + 2) * 2048 + lane * 8;
    const unsigned short* nkpB = Kb + (size_t)(2 * kb2 + 3) * 2048 + lane * 8;
    const unsigned short* nvpB = Vb + (size_t)(2 * kb2 + 3) * 2048 + lane * 8;
#pragma unroll
    for (int sb = 0; sb < 4; ++sb) {
      // ---- chain A ----
      {
        const short8 t0 = vvA[(sb >> 1)];
        const short8 t1 = vvA[2 + (sb >> 1)];
        short4v vf0, vf1;
        if (sb & 1) {
          vf0 = __builtin_shufflevector(t0, t0, 4, 5, 6, 7);
          vf1 = __builtin_shufflevector(t1, t1, 4, 5, 6, 7);
        } else {
          vf0 = __builtin_shufflevector(t0, t0, 0, 1, 2, 3);
          vf1 = __builtin_shufflevector(t1, t1, 0, 1, 2, 3);
        }
        f32x4 st[2];
#pragma unroll
        for (int mt = 0; mt < 2; ++mt) {
          f32x4 z = {0.f, 0.f, 0.f, 0.f};
          st[mt] = __builtin_amdgcn_mfma_f32_16x16x32_bf16(kfA[sb], qf[mt], z, 0, 0, 0);
        }
        kfA[sb] = *(const short8*)(nkpA + sb * 512);
        if (sb == 1) {
          vvA[0] = *(const short8*)(nvpA + 0 * 512);
          vvA[2] = *(const short8*)(nvpA + 2 * 512);
        }
        if (sb == 3) {
          vvA[1] = *(const short8*)(nvpA + 1 * 512);
          vvA[3] = *(const short8*)(nvpA + 3 * 512);
        }
#pragma unroll
        for (int mt = 0; mt < 2; ++mt) {
          const float p0 = __builtin_amdgcn_exp2f(st[mt][0]);
          const float p1 = __builtin_amdgcn_exp2f(st[mt][1]);
          const float p2 = __builtin_amdgcn_exp2f(st[mt][2]);
          const float p3 = __builtin_amdgcn_exp2f(st[mt][3]);
          int2 pi;
          pi.x = pack_bf16tr(p0, p1);
          pi.y = pack_bf16tr(p2, p3);
          const short4v pf = __builtin_bit_cast(short4v, pi);
          lsum_acc[mt] = __builtin_amdgcn_mfma_f32_16x16x16bf16_1k(pf, onesf, lsum_acc[mt], 0, 0, 0);
          acc[mt][0] = __builtin_amdgcn_mfma_f32_16x16x16bf16_1k(pf, vf0, acc[mt][0], 0, 0, 0);
          acc[mt][1] = __builtin_amdgcn_mfma_f32_16x16x16bf16_1k(pf, vf1, acc[mt][1], 0, 0, 0);
        }
      }
      // ---- chain B (independent registers; shared accumulators) ----
      {
        const short8 t0 = vvB[(sb >> 1)];
        const short8 t1 = vvB[2 + (sb >> 1)];
        short4v vf0, vf1;
        if (sb & 1) {
          vf0 = __builtin_shufflevector(t0, t0, 4, 5, 6, 7);
          vf1 = __builtin_shufflevector(t1, t1, 4, 5, 6, 7);
        } else {
          vf0 = __builtin_shufflevector(t0, t0, 0, 1, 2, 3);
          vf1 = __builtin_shufflevector(t1, t1, 0, 1, 2, 3);
        }
        f32x4 st[2];
#pragma unroll
        for (int mt = 0; mt < 2; ++mt) {
          f32x4 z = {0.f, 0.f, 0.f, 0.f};
          st[mt] = __builtin_amdgcn_mfma_f32_16x16x32_bf16(kfB[sb], qf[mt], z, 0, 0, 0);
        }
        kfB[sb] = *(const short8*)(nkpB + sb * 512);
        if (sb == 1) {
          vvB[0] = *(const short8*)(nvpB + 0 * 512);
          vvB[2] = *(const short8*)(nvpB + 2 * 512);
        }
        if (sb == 3) {
          vvB[1] = *(const short8*)(nvpB + 1 * 512);
          vvB[3] = *(const short8*)(nvpB + 3 * 512);
        }
#pragma unroll
        for (int mt = 0; mt < 2; ++mt) {
          const float p0 = __builtin_amdgcn_exp2f(st[mt][0]);
          const float p1 = __builtin_amdgcn_exp2f(st[mt][1]);
          const float p2 = __builtin_amdgcn_exp2f(st[mt][2]);
          const float p3 = __builtin_amdgcn_exp2f(st[mt][3]);
          int2 pi;
          pi.x = pack_bf16tr(p0, p1);
          pi.y = pack_bf16tr(p2, p3);
          const short4v pf = __builtin_bit_cast(short4v, pi);
          lsum_acc[mt] = __builtin_amdgcn_mfma_f32_16x16x16bf16_1k(pf, onesf, lsum_acc[mt], 0, 0, 0);
          acc[mt][0] = __builtin_amdgcn_mfma_f32_16x16x16bf16_1k(pf, vf0, acc[mt][0], 0, 0, 0);
          acc[mt][1] = __builtin_amdgcn_mfma_f32_16x16x16bf16_1k(pf, vf1, acc[mt][1], 0, 0, 0);
        }
      }
    }
  }

  // Normalize + direct store. acc C-layout: col=lc=d, row=quad*4+r=q (+mt*16);
  // lsum_acc rows identical -> per-lane elementwise, no shuffles.
  const int chbase = (nh >> 3) * 256 + (nh & 7) * 32;
#pragma unroll
  for (int mt = 0; mt < 2; ++mt) {
    f32x4 is;
#pragma unroll
    for (int r = 0; r < 4; ++r) is[r] = 1.0f / lsum_acc[mt][r];
    const int tb = qw * 32 + mt * 16 + quad * 4;
#pragma unroll
    for (int dt = 0; dt < 2; ++dt) {
      f32x4 ov;
#pragma unroll
      for (int r = 0; r < 4; ++r) ov[r] = acc[mt][dt][r] * is[r];
      *(f32x4*)(out + (size_t)(chbase + dt * 16 + lc) * 2048 + tb) = ov;
    }
  }
}

extern "C" void kernel_launch(void* const* d_in, const int* in_sizes, int n_in,
                              void* d_out, int out_size, void* d_ws, size_t ws_size,
                              hipStream_t stream) {
  const float* x = (const float*)d_in[0];
  const float* Wq = (const float*)d_in[1];
  const float* Wk = (const float*)d_in[2];
  const float* Wv = (const float*)d_in[3];
  unsigned short* ws = (unsigned short*)d_ws;
  float* out = (float*)d_out;
  (void)in_sizes; (void)n_in; (void)out_size; (void)ws_size;

  pack_kernel<<<1120, 256, 0, stream>>>(x, Wq, Wk, Wv, ws);
  proj_kernel<<<dim3(64, 4, 3), 256, 0, stream>>>(ws);
  attn_kernel<<<1024, 128, 0, stream>>>(ws, out);
}